// Round 4
// baseline (13856.075 us; speedup 1.0000x reference)
//
#include <hip/hip_runtime.h>

// Problem constants
#define B_ 32
#define S_ 2048
#define DA 32
#define DH 128
#define DS 64
#define DS2 4096

template <int CTRL>
__device__ __forceinline__ float dpp_add(float x) {
  int t = __builtin_amdgcn_update_dpp(0, __float_as_int(x), CTRL, 0xF, 0xF, true);
  return x + __int_as_float(t);
}
__device__ __forceinline__ float rl(float x, int lane) {
  return __int_as_float(__builtin_amdgcn_readlane(__float_as_int(x), lane));
}
// sum across 64 lanes, result uniform in all lanes (4 DPP + 4 readlane)
__device__ __forceinline__ float wave_sum64(float x) {
  x = dpp_add<0xB1>(x);   // quad_perm xor1
  x = dpp_add<0x4E>(x);   // quad_perm xor2
  x = dpp_add<0x141>(x);  // row_half_mirror (combine 4-groups)
  x = dpp_add<0x140>(x);  // row_mirror (combine 8-groups) -> row-of-16 uniform
  return (rl(x, 0) + rl(x, 16)) + (rl(x, 32) + rl(x, 48));
}

// ---------------------------------------------------------------------------
// Kernel 1: h1t[f][tok] = relu(relu(actions@w0 + b0)@w1 + b1)  (TRANSPOSED out)
// 64 tokens per block, 256 threads, 4x8 microtile. M = SC*32 tokens per chunk.
// ---------------------------------------------------------------------------
__global__ __launch_bounds__(256) void k_mlp01(
    const float* __restrict__ actions, const float* __restrict__ w0,
    const float* __restrict__ b0, const float* __restrict__ w1,
    const float* __restrict__ b1, float* __restrict__ h1t,
    int s_base, int M)
{
  __shared__ float a_t[DA][64];    // [k][tok]   8 KB
  __shared__ float w0_l[DA][DH];   // [k][f]    16 KB
  __shared__ float h0t[DH][64];    // [f][tok]  32 KB
  const int tid = threadIdx.x;
  const int m0 = blockIdx.x * 64;  // chunk-local token offset

#pragma unroll
  for (int q = 0; q < 2; ++q) {
    int g = tid + 256 * q;              // float4 id, 512 total
    int tok = g >> 3, kq = g & 7;
    int tl = m0 + tok;
    int b = tl & 31, s = s_base + (tl >> 5);
    float4 v = *(const float4*)(actions + ((size_t)b * S_ + s) * DA + 4 * kq);
    a_t[4 * kq + 0][tok] = v.x; a_t[4 * kq + 1][tok] = v.y;
    a_t[4 * kq + 2][tok] = v.z; a_t[4 * kq + 3][tok] = v.w;
  }
#pragma unroll
  for (int q = 0; q < 4; ++q) {
    int g = tid + 256 * q;              // 1024 float4
    ((float4*)&w0_l[0][0])[g] = ((const float4*)w0)[g];
  }
  __syncthreads();

  const int tm = tid & 15;   // token quad
  const int tn = tid >> 4;   // feature octet (0..15)

  float acc[4][8];
#pragma unroll
  for (int mi = 0; mi < 4; ++mi)
#pragma unroll
    for (int ni = 0; ni < 8; ++ni) acc[mi][ni] = 0.f;

#pragma unroll 4
  for (int k = 0; k < DA; ++k) {
    float4 a4 = *(const float4*)&a_t[k][4 * tm];
    float4 wa = *(const float4*)&w0_l[k][8 * tn];
    float4 wb = *(const float4*)&w0_l[k][8 * tn + 4];
    float av[4] = {a4.x, a4.y, a4.z, a4.w};
    float wv[8] = {wa.x, wa.y, wa.z, wa.w, wb.x, wb.y, wb.z, wb.w};
#pragma unroll
    for (int mi = 0; mi < 4; ++mi)
#pragma unroll
      for (int ni = 0; ni < 8; ++ni) acc[mi][ni] += av[mi] * wv[ni];
  }
  {
    float4 ba = *(const float4*)(b0 + 8 * tn);
    float4 bb = *(const float4*)(b0 + 8 * tn + 4);
    float bv[8] = {ba.x, ba.y, ba.z, ba.w, bb.x, bb.y, bb.z, bb.w};
#pragma unroll
    for (int mi = 0; mi < 4; ++mi)
#pragma unroll
      for (int ni = 0; ni < 8; ++ni)
        h0t[8 * tn + ni][4 * tm + mi] = fmaxf(acc[mi][ni] + bv[ni], 0.f);
  }
  __syncthreads();

  float acc1[4][8];
#pragma unroll
  for (int mi = 0; mi < 4; ++mi)
#pragma unroll
    for (int ni = 0; ni < 8; ++ni) acc1[mi][ni] = 0.f;

#pragma unroll 4
  for (int k = 0; k < DH; ++k) {
    float4 h4 = *(const float4*)&h0t[k][4 * tm];
    float4 wa = *(const float4*)(w1 + (size_t)k * DH + 8 * tn);
    float4 wb = *(const float4*)(w1 + (size_t)k * DH + 8 * tn + 4);
    float av[4] = {h4.x, h4.y, h4.z, h4.w};
    float wv[8] = {wa.x, wa.y, wa.z, wa.w, wb.x, wb.y, wb.z, wb.w};
#pragma unroll
    for (int mi = 0; mi < 4; ++mi)
#pragma unroll
      for (int ni = 0; ni < 8; ++ni) acc1[mi][ni] += av[mi] * wv[ni];
  }
  {
    float4 ba = *(const float4*)(b1 + 8 * tn);
    float4 bb = *(const float4*)(b1 + 8 * tn + 4);
    float bv[8] = {ba.x, ba.y, ba.z, ba.w, bb.x, bb.y, bb.z, bb.w};
#pragma unroll
    for (int ni = 0; ni < 8; ++ni) {
      float4 o;
      o.x = fmaxf(acc1[0][ni] + bv[ni], 0.f);
      o.y = fmaxf(acc1[1][ni] + bv[ni], 0.f);
      o.z = fmaxf(acc1[2][ni] + bv[ni], 0.f);
      o.w = fmaxf(acc1[3][ni] + bv[ni], 0.f);
      // transposed store: h1t[feat][token], coalesced across tm
      *(float4*)(h1t + (size_t)(8 * tn + ni) * M + m0 + 4 * tm) = o;
    }
  }
}

// ---------------------------------------------------------------------------
// Kernel 2: trans = h1t^T @ w2 + b2.  fp32, 256 threads, tile M128 x N256,
// microtile 8m x 16n (128 FMA per 6 b128 -> VALU-bound, not LDS-bound),
// K-tile 16 double-buffered (48 KB LDS), ONE barrier per K-tile.
// Thread map: mg=tid>>4 (A-reads broadcast), ng=tid&15 with n interleaved
// n = 64q+4ng+r  -> B-reads conflict-free AND stores are 256 B contiguous
// per 16-lane group (full 128-B lines per store instruction).
// ---------------------------------------------------------------------------
#define TKK 16
__global__ __launch_bounds__(256, 2) void k_trans(
    const float* __restrict__ h1t, const float* __restrict__ w2,
    const float* __restrict__ b2, float* __restrict__ trans, int M)
{
  __shared__ float As[2][TKK][128];  // 8 KB x2
  __shared__ float Bs[2][TKK][256];  // 16 KB x2
  const int tid = threadIdx.x;
  const int n0 = blockIdx.x * 256;
  const int m0 = blockIdx.y * 128;

  float4 ra[2], rb[4];
  auto gload = [&](int t) {
#pragma unroll
    for (int q = 0; q < 2; ++q) {
      int g = tid + 256 * q;
      int k = g >> 5, mq = g & 31;     // 16 k-rows x 32 quads
      ra[q] = *(const float4*)(h1t + (size_t)(t * TKK + k) * M + m0 + 4 * mq);
    }
#pragma unroll
    for (int q = 0; q < 4; ++q) {
      int g = tid + 256 * q;
      int k = g >> 6, nq = g & 63;     // 16 k-rows x 64 quads
      rb[q] = *(const float4*)(w2 + (size_t)(t * TKK + k) * DS2 + n0 + 4 * nq);
    }
  };
  auto lwrite = [&](int buf) {
#pragma unroll
    for (int q = 0; q < 2; ++q) {
      int g = tid + 256 * q;
      int k = g >> 5, mq = g & 31;
      *(float4*)&As[buf][k][4 * mq] = ra[q];
    }
#pragma unroll
    for (int q = 0; q < 4; ++q) {
      int g = tid + 256 * q;
      int k = g >> 6, nq = g & 63;
      *(float4*)&Bs[buf][k][4 * nq] = rb[q];
    }
  };

  gload(0);
  lwrite(0);

  const int mg = tid >> 4;   // 0..15, m = 8*mg+mi  (broadcast A within 16-lane group)
  const int ng = tid & 15;   // n = 64*q + 4*ng + r
  float acc[8][16];
#pragma unroll
  for (int mi = 0; mi < 8; ++mi)
#pragma unroll
    for (int ni = 0; ni < 16; ++ni) acc[mi][ni] = 0.f;

  for (int t = 0; t < DH / TKK; ++t) {
    if (t < DH / TKK - 1) gload(t + 1);
    __syncthreads();
    const int buf = t & 1;
#pragma unroll
    for (int k = 0; k < TKK; ++k) {
      float4 a0 = *(const float4*)&As[buf][k][8 * mg];
      float4 a1 = *(const float4*)&As[buf][k][8 * mg + 4];
      float av[8] = {a0.x, a0.y, a0.z, a0.w, a1.x, a1.y, a1.z, a1.w};
      float bv[16];
#pragma unroll
      for (int q = 0; q < 4; ++q) {
        float4 b4 = *(const float4*)&Bs[buf][k][64 * q + 4 * ng];
        bv[4 * q + 0] = b4.x; bv[4 * q + 1] = b4.y;
        bv[4 * q + 2] = b4.z; bv[4 * q + 3] = b4.w;
      }
#pragma unroll
      for (int mi = 0; mi < 8; ++mi)
#pragma unroll
        for (int ni = 0; ni < 16; ++ni) acc[mi][ni] += av[mi] * bv[ni];
    }
    if (t < DH / TKK - 1) lwrite((t + 1) & 1);
  }

  float bv[16];
#pragma unroll
  for (int q = 0; q < 4; ++q) {
    float4 b4 = *(const float4*)(b2 + n0 + 64 * q + 4 * ng);
    bv[4 * q + 0] = b4.x; bv[4 * q + 1] = b4.y;
    bv[4 * q + 2] = b4.z; bv[4 * q + 3] = b4.w;
  }
#pragma unroll
  for (int mi = 0; mi < 8; ++mi) {
    float* dst = trans + (size_t)(m0 + 8 * mg + mi) * DS2 + n0;
#pragma unroll
    for (int q = 0; q < 4; ++q) {
      float4 o;
      o.x = acc[mi][4 * q + 0] + bv[4 * q + 0];
      o.y = acc[mi][4 * q + 1] + bv[4 * q + 1];
      o.z = acc[mi][4 * q + 2] + bv[4 * q + 2];
      o.w = acc[mi][4 * q + 3] + bv[4 * q + 3];
      *(float4*)(dst + 64 * q + 4 * ng) = o;
    }
  }
}

// ---------------------------------------------------------------------------
// Kernel 3: sequential RNN.  ONE WAVE per batch element — no barrier, no LDS.
// Lane = output feature j.  h_i broadcast via v_readlane (const lane index);
// T[s] in registers, ring of 4 step-slots (64 VGPR each), prefetch depth 4.
// 64-thread block => 1 wave/SIMD => ~512-VGPR budget, no spill.
// ---------------------------------------------------------------------------
__global__ __launch_bounds__(64) void k_rnn(
    const float* __restrict__ trans, const float* __restrict__ init_hidden,
    float* __restrict__ hstate, float* __restrict__ out,
    int s_base, int SC, int chunk)
{
  const int lane = threadIdx.x;
  const int b = blockIdx.x;

  float h;
  if (chunk == 0) {
    float ih = init_hidden[lane];
    float ss = wave_sum64(ih * ih);
    h = ih / fmaxf(sqrtf(ss), 1e-12f);
  } else {
    h = hstate[b * DS + lane];
  }

  // T element for step s: trans[(s*32 + b)*4096 + i*64 + lane]
  const float* tb = trans + (size_t)b * DS2 + lane;
  float tre[4][64];
#pragma unroll
  for (int d = 0; d < 4; ++d) {
    const float* p = tb + (size_t)d * (32 * DS2);
#pragma unroll
    for (int i = 0; i < 64; ++i) tre[d][i] = p[i * DS];
  }

  float* outp = out + ((size_t)b * S_ + s_base) * DS + lane;

  for (int s0 = 0; s0 < SC; s0 += 4) {
#pragma unroll
    for (int d = 0; d < 4; ++d) {
      const int s = s0 + d;
      // full matvec in one wave: h'_j = sum_i h_i * T[i][j], 4 chains
      float p0 = 0.f, p1 = 0.f, p2 = 0.f, p3 = 0.f;
#pragma unroll
      for (int i = 0; i < 64; i += 4) {
        p0 += rl(h, i + 0) * tre[d][i + 0];
        p1 += rl(h, i + 1) * tre[d][i + 1];
        p2 += rl(h, i + 2) * tre[d][i + 2];
        p3 += rl(h, i + 3) * tre[d][i + 3];
      }
      // prefetch T[s+4] into the slot just consumed
      int sp = s + 4; if (sp > SC - 1) sp = SC - 1;
      {
        const float* p = tb + (size_t)sp * (32 * DS2);
#pragma unroll
        for (int i = 0; i < 64; ++i) tre[d][i] = p[i * DS];
      }
      float r = fmaxf((p0 + p1) + (p2 + p3), 0.f);
      float ss = wave_sum64(r * r);
      h = r / fmaxf(sqrtf(ss), 1e-12f);
      outp[(size_t)s * DS] = h;
    }
  }
  hstate[b * DS + lane] = h;
}

// ---------------------------------------------------------------------------
extern "C" void kernel_launch(void* const* d_in, const int* in_sizes, int n_in,
                              void* d_out, int out_size, void* d_ws, size_t ws_size,
                              hipStream_t stream) {
  const float* actions     = (const float*)d_in[0];
  const float* w0          = (const float*)d_in[1];
  const float* b0          = (const float*)d_in[2];
  const float* w1          = (const float*)d_in[3];
  const float* b1          = (const float*)d_in[4];
  const float* w2          = (const float*)d_in[5];
  const float* b2          = (const float*)d_in[6];
  const float* init_hidden = (const float*)d_in[7];
  float* out = (float*)d_out;

  // pick the largest sequence chunk whose transitions fit in ws
  int SC = 2048;
  while (SC > 4) {
    size_t need = (size_t)SC * 32 * DS2 * 4   // transitions chunk
                + (size_t)SC * 32 * DH * 4    // h1t chunk
                + 64 * 4;                     // hidden-state carry
    if (need <= ws_size) break;
    SC >>= 1;
  }
  float* trans  = (float*)d_ws;
  float* h1t    = trans + (size_t)SC * 32 * DS2;
  float* hstate = h1t + (size_t)SC * 32 * DH;

  const int M = SC * 32;
  const int nch = S_ / SC;
  for (int c = 0; c < nch; ++c) {
    int s_base = c * SC;
    hipLaunchKernelGGL(k_mlp01, dim3(M / 64), dim3(256), 0, stream,
                       actions, w0, b0, w1, b1, h1t, s_base, M);
    hipLaunchKernelGGL(k_trans, dim3(DS2 / 256, M / 128), dim3(256), 0, stream,
                       h1t, w2, b2, trans, M);
    hipLaunchKernelGGL(k_rnn, dim3(32), dim3(64), 0, stream,
                       trans, init_hidden, hstate, out, s_base, SC, c);
  }
}

// Round 5
// 5396.437 us; speedup vs baseline: 2.5676x; 2.5676x over previous
//
#include <hip/hip_runtime.h>

// Problem constants
#define B_ 32
#define S_ 2048
#define DA 32
#define DH 128
#define DS 64
#define DS2 4096

template <int CTRL>
__device__ __forceinline__ float dpp_add(float x) {
  int t = __builtin_amdgcn_update_dpp(0, __float_as_int(x), CTRL, 0xF, 0xF, true);
  return x + __int_as_float(t);
}
__device__ __forceinline__ float rl(float x, int lane) {
  return __int_as_float(__builtin_amdgcn_readlane(__float_as_int(x), lane));
}
// sum across 64 lanes, result uniform in all lanes (4 DPP + 4 readlane)
__device__ __forceinline__ float wave_sum64(float x) {
  x = dpp_add<0xB1>(x);   // quad_perm xor1
  x = dpp_add<0x4E>(x);   // quad_perm xor2
  x = dpp_add<0x141>(x);  // row_half_mirror (combine 4-groups)
  x = dpp_add<0x140>(x);  // row_mirror (combine 8-groups) -> row-of-16 uniform
  return (rl(x, 0) + rl(x, 16)) + (rl(x, 32) + rl(x, 48));
}

// ---------------------------------------------------------------------------
// Kernel 1: h1t[f][tok] = relu(relu(actions@w0 + b0)@w1 + b1)  (TRANSPOSED out)
// 64 tokens per block, 256 threads, 4x8 microtile. M = SC*32 tokens per chunk.
// ---------------------------------------------------------------------------
__global__ __launch_bounds__(256) void k_mlp01(
    const float* __restrict__ actions, const float* __restrict__ w0,
    const float* __restrict__ b0, const float* __restrict__ w1,
    const float* __restrict__ b1, float* __restrict__ h1t,
    int s_base, int M)
{
  __shared__ float a_t[DA][64];    // [k][tok]   8 KB
  __shared__ float w0_l[DA][DH];   // [k][f]    16 KB
  __shared__ float h0t[DH][64];    // [f][tok]  32 KB
  const int tid = threadIdx.x;
  const int m0 = blockIdx.x * 64;  // chunk-local token offset

#pragma unroll
  for (int q = 0; q < 2; ++q) {
    int g = tid + 256 * q;              // float4 id, 512 total
    int tok = g >> 3, kq = g & 7;
    int tl = m0 + tok;
    int b = tl & 31, s = s_base + (tl >> 5);
    float4 v = *(const float4*)(actions + ((size_t)b * S_ + s) * DA + 4 * kq);
    a_t[4 * kq + 0][tok] = v.x; a_t[4 * kq + 1][tok] = v.y;
    a_t[4 * kq + 2][tok] = v.z; a_t[4 * kq + 3][tok] = v.w;
  }
#pragma unroll
  for (int q = 0; q < 4; ++q) {
    int g = tid + 256 * q;              // 1024 float4
    ((float4*)&w0_l[0][0])[g] = ((const float4*)w0)[g];
  }
  __syncthreads();

  const int tm = tid & 15;   // token quad
  const int tn = tid >> 4;   // feature octet (0..15)

  float acc[4][8];
#pragma unroll
  for (int mi = 0; mi < 4; ++mi)
#pragma unroll
    for (int ni = 0; ni < 8; ++ni) acc[mi][ni] = 0.f;

#pragma unroll 4
  for (int k = 0; k < DA; ++k) {
    float4 a4 = *(const float4*)&a_t[k][4 * tm];
    float4 wa = *(const float4*)&w0_l[k][8 * tn];
    float4 wb = *(const float4*)&w0_l[k][8 * tn + 4];
    float av[4] = {a4.x, a4.y, a4.z, a4.w};
    float wv[8] = {wa.x, wa.y, wa.z, wa.w, wb.x, wb.y, wb.z, wb.w};
#pragma unroll
    for (int mi = 0; mi < 4; ++mi)
#pragma unroll
      for (int ni = 0; ni < 8; ++ni) acc[mi][ni] += av[mi] * wv[ni];
  }
  {
    float4 ba = *(const float4*)(b0 + 8 * tn);
    float4 bb = *(const float4*)(b0 + 8 * tn + 4);
    float bv[8] = {ba.x, ba.y, ba.z, ba.w, bb.x, bb.y, bb.z, bb.w};
#pragma unroll
    for (int mi = 0; mi < 4; ++mi)
#pragma unroll
      for (int ni = 0; ni < 8; ++ni)
        h0t[8 * tn + ni][4 * tm + mi] = fmaxf(acc[mi][ni] + bv[ni], 0.f);
  }
  __syncthreads();

  float acc1[4][8];
#pragma unroll
  for (int mi = 0; mi < 4; ++mi)
#pragma unroll
    for (int ni = 0; ni < 8; ++ni) acc1[mi][ni] = 0.f;

#pragma unroll 4
  for (int k = 0; k < DH; ++k) {
    float4 h4 = *(const float4*)&h0t[k][4 * tm];
    float4 wa = *(const float4*)(w1 + (size_t)k * DH + 8 * tn);
    float4 wb = *(const float4*)(w1 + (size_t)k * DH + 8 * tn + 4);
    float av[4] = {h4.x, h4.y, h4.z, h4.w};
    float wv[8] = {wa.x, wa.y, wa.z, wa.w, wb.x, wb.y, wb.z, wb.w};
#pragma unroll
    for (int mi = 0; mi < 4; ++mi)
#pragma unroll
      for (int ni = 0; ni < 8; ++ni) acc1[mi][ni] += av[mi] * wv[ni];
  }
  {
    float4 ba = *(const float4*)(b1 + 8 * tn);
    float4 bb = *(const float4*)(b1 + 8 * tn + 4);
    float bv[8] = {ba.x, ba.y, ba.z, ba.w, bb.x, bb.y, bb.z, bb.w};
#pragma unroll
    for (int ni = 0; ni < 8; ++ni) {
      float4 o;
      o.x = fmaxf(acc1[0][ni] + bv[ni], 0.f);
      o.y = fmaxf(acc1[1][ni] + bv[ni], 0.f);
      o.z = fmaxf(acc1[2][ni] + bv[ni], 0.f);
      o.w = fmaxf(acc1[3][ni] + bv[ni], 0.f);
      // transposed store: h1t[feat][token], coalesced across tm
      *(float4*)(h1t + (size_t)(8 * tn + ni) * M + m0 + 4 * tm) = o;
    }
  }
}

// ---------------------------------------------------------------------------
// Kernel 2: trans = h1t^T @ w2 + b2.  fp32, 256 threads, tile M128 x N256,
// microtile 8m x 16n (128 FMA per 6 b128, A/B reads broadcast-heavy ->
// VALU-bound).  K-tile 16 double-buffered (48 KB LDS).
// Loop order per tile: sync; gload(t+1); compute(t); lwrite(t+1) — the
// barrier sees an EMPTY vmcnt queue (loads consumed by lwrite post-compute),
// so global latency is hidden behind the ~2000-cyc compute phase.
// __launch_bounds__(256,1): VGPR cap 512; actual ~220 -> 2 waves/SIMD.
// ---------------------------------------------------------------------------
#define TKK 16
__global__ __launch_bounds__(256, 1) void k_trans(
    const float* __restrict__ h1t, const float* __restrict__ w2,
    const float* __restrict__ b2, float* __restrict__ trans, int M)
{
  __shared__ float As[2][TKK][128];  // 8 KB x2
  __shared__ float Bs[2][TKK][256];  // 16 KB x2
  const int tid = threadIdx.x;
  const int n0 = blockIdx.x * 256;
  const int m0 = blockIdx.y * 128;

  float4 ra[2], rb[4];
  auto gload = [&](int t) {
#pragma unroll
    for (int q = 0; q < 2; ++q) {
      int g = tid + 256 * q;
      int k = g >> 5, mq = g & 31;     // 16 k-rows x 32 quads
      ra[q] = *(const float4*)(h1t + (size_t)(t * TKK + k) * M + m0 + 4 * mq);
    }
#pragma unroll
    for (int q = 0; q < 4; ++q) {
      int g = tid + 256 * q;
      int k = g >> 6, nq = g & 63;     // 16 k-rows x 64 quads
      rb[q] = *(const float4*)(w2 + (size_t)(t * TKK + k) * DS2 + n0 + 4 * nq);
    }
  };
  auto lwrite = [&](int buf) {
#pragma unroll
    for (int q = 0; q < 2; ++q) {
      int g = tid + 256 * q;
      int k = g >> 5, mq = g & 31;
      *(float4*)&As[buf][k][4 * mq] = ra[q];
    }
#pragma unroll
    for (int q = 0; q < 4; ++q) {
      int g = tid + 256 * q;
      int k = g >> 6, nq = g & 63;
      *(float4*)&Bs[buf][k][4 * nq] = rb[q];
    }
  };

  gload(0);
  lwrite(0);

  const int mg = tid >> 4;   // 0..15, m = 8*mg+mi  (A broadcast per 16-lane grp)
  const int ng = tid & 15;   // n = 64*q + 4*ng + r
  float acc[8][16];
#pragma unroll
  for (int mi = 0; mi < 8; ++mi)
#pragma unroll
    for (int ni = 0; ni < 16; ++ni) acc[mi][ni] = 0.f;

  for (int t = 0; t < DH / TKK; ++t) {
    __syncthreads();                       // lwrite(t) visible; vmcnt empty
    if (t < DH / TKK - 1) gload(t + 1);    // in flight during compute
    const int buf = t & 1;
#pragma unroll
    for (int k = 0; k < TKK; ++k) {
      float4 a0 = *(const float4*)&As[buf][k][8 * mg];
      float4 a1 = *(const float4*)&As[buf][k][8 * mg + 4];
      float av[8] = {a0.x, a0.y, a0.z, a0.w, a1.x, a1.y, a1.z, a1.w};
      float bv[16];
#pragma unroll
      for (int q = 0; q < 4; ++q) {
        float4 b4 = *(const float4*)&Bs[buf][k][64 * q + 4 * ng];
        bv[4 * q + 0] = b4.x; bv[4 * q + 1] = b4.y;
        bv[4 * q + 2] = b4.z; bv[4 * q + 3] = b4.w;
      }
#pragma unroll
      for (int mi = 0; mi < 8; ++mi)
#pragma unroll
        for (int ni = 0; ni < 16; ++ni) acc[mi][ni] += av[mi] * bv[ni];
    }
    if (t < DH / TKK - 1) lwrite((t + 1) & 1);  // vmcnt wait lands here (cheap)
  }

  float bv[16];
#pragma unroll
  for (int q = 0; q < 4; ++q) {
    float4 b4 = *(const float4*)(b2 + n0 + 64 * q + 4 * ng);
    bv[4 * q + 0] = b4.x; bv[4 * q + 1] = b4.y;
    bv[4 * q + 2] = b4.z; bv[4 * q + 3] = b4.w;
  }
#pragma unroll
  for (int mi = 0; mi < 8; ++mi) {
    float* dst = trans + (size_t)(m0 + 8 * mg + mi) * DS2 + n0;
#pragma unroll
    for (int q = 0; q < 4; ++q) {
      float4 o;
      o.x = acc[mi][4 * q + 0] + bv[4 * q + 0];
      o.y = acc[mi][4 * q + 1] + bv[4 * q + 1];
      o.z = acc[mi][4 * q + 2] + bv[4 * q + 2];
      o.w = acc[mi][4 * q + 3] + bv[4 * q + 3];
      *(float4*)(dst + 64 * q + 4 * ng) = o;   // 256 B contiguous / 16 lanes
    }
  }
}

// ---------------------------------------------------------------------------
// Kernel 3: sequential RNN.  ONE WAVE per batch element — no barrier, no LDS.
// Lane = output feature j.  h_i broadcast via v_readlane (uniform index);
// T[s] in registers, ring of 4 step-slots (64 VGPR each), prefetch depth 4.
// __launch_bounds__(64,1): VGPR cap 512; tre needs 256 + ~40 misc -> ~300,
// fits WITHOUT spill (R4's 152-reg cap was the 30 ms disaster).
// ---------------------------------------------------------------------------
__global__ __launch_bounds__(64, 1) void k_rnn(
    const float* __restrict__ trans, const float* __restrict__ init_hidden,
    float* __restrict__ hstate, float* __restrict__ out,
    int s_base, int SC, int chunk)
{
  const int lane = threadIdx.x;
  const int b = blockIdx.x;

  float h;
  if (chunk == 0) {
    float ih = init_hidden[lane];
    float ss = wave_sum64(ih * ih);
    h = ih / fmaxf(sqrtf(ss), 1e-12f);
  } else {
    h = hstate[b * DS + lane];
  }

  // T element for step s: trans[(s*32 + b)*4096 + i*64 + lane]
  const float* tb = trans + (size_t)b * DS2 + lane;
  float tre[4][64];
#pragma unroll
  for (int d = 0; d < 4; ++d) {
    const float* p = tb + (size_t)d * (32 * DS2);
#pragma unroll
    for (int i = 0; i < 64; ++i) tre[d][i] = p[i * DS];
  }

  float* outp = out + ((size_t)b * S_ + s_base) * DS + lane;

  for (int s0 = 0; s0 < SC; s0 += 4) {
#pragma unroll
    for (int d = 0; d < 4; ++d) {
      const int s = s0 + d;
      // full matvec in one wave: h'_j = sum_i h_i * T[i][j], 4 chains
      float p0 = 0.f, p1 = 0.f, p2 = 0.f, p3 = 0.f;
#pragma unroll
      for (int i = 0; i < 64; i += 4) {
        p0 += rl(h, i + 0) * tre[d][i + 0];
        p1 += rl(h, i + 1) * tre[d][i + 1];
        p2 += rl(h, i + 2) * tre[d][i + 2];
        p3 += rl(h, i + 3) * tre[d][i + 3];
      }
      // prefetch T[s+4] into the slot just consumed (covers ~4 steps of
      // latency; loads issue post-consumption, complete before reuse)
      int sp = s + 4; if (sp > SC - 1) sp = SC - 1;
      {
        const float* p = tb + (size_t)sp * (32 * DS2);
#pragma unroll
        for (int i = 0; i < 64; ++i) tre[d][i] = p[i * DS];
      }
      float r = fmaxf((p0 + p1) + (p2 + p3), 0.f);
      float ss = wave_sum64(r * r);
      h = r / fmaxf(sqrtf(ss), 1e-12f);
      outp[(size_t)s * DS] = h;
    }
  }
  hstate[b * DS + lane] = h;
}

// ---------------------------------------------------------------------------
extern "C" void kernel_launch(void* const* d_in, const int* in_sizes, int n_in,
                              void* d_out, int out_size, void* d_ws, size_t ws_size,
                              hipStream_t stream) {
  const float* actions     = (const float*)d_in[0];
  const float* w0          = (const float*)d_in[1];
  const float* b0          = (const float*)d_in[2];
  const float* w1          = (const float*)d_in[3];
  const float* b1          = (const float*)d_in[4];
  const float* w2          = (const float*)d_in[5];
  const float* b2          = (const float*)d_in[6];
  const float* init_hidden = (const float*)d_in[7];
  float* out = (float*)d_out;

  // pick the largest sequence chunk whose transitions fit in ws
  int SC = 2048;
  while (SC > 4) {
    size_t need = (size_t)SC * 32 * DS2 * 4   // transitions chunk
                + (size_t)SC * 32 * DH * 4    // h1t chunk
                + 64 * 4;                     // hidden-state carry
    if (need <= ws_size) break;
    SC >>= 1;
  }
  float* trans  = (float*)d_ws;
  float* h1t    = trans + (size_t)SC * 32 * DS2;
  float* hstate = h1t + (size_t)SC * 32 * DH;

  const int M = SC * 32;
  const int nch = S_ / SC;
  for (int c = 0; c < nch; ++c) {
    int s_base = c * SC;
    hipLaunchKernelGGL(k_mlp01, dim3(M / 64), dim3(256), 0, stream,
                       actions, w0, b0, w1, b1, h1t, s_base, M);
    hipLaunchKernelGGL(k_trans, dim3(DS2 / 256, M / 128), dim3(256), 0, stream,
                       h1t, w2, b2, trans, M);
    hipLaunchKernelGGL(k_rnn, dim3(32), dim3(64), 0, stream,
                       trans, init_hidden, hstate, out, s_base, SC, c);
  }
}

// Round 6
// 2360.219 us; speedup vs baseline: 5.8707x; 2.2864x over previous
//
#include <hip/hip_runtime.h>

// Problem constants
#define B_ 32
#define S_ 2048
#define DA 32
#define DH 128
#define DS 64
#define DS2 4096

template <int CTRL>
__device__ __forceinline__ float dpp_add(float x) {
  int t = __builtin_amdgcn_update_dpp(0, __float_as_int(x), CTRL, 0xF, 0xF, true);
  return x + __int_as_float(t);
}
// sum over the 16 lanes of each row, result uniform within the row
__device__ __forceinline__ float row_sum16(float x) {
  x = dpp_add<0xB1>(x);   // xor1
  x = dpp_add<0x4E>(x);   // xor2
  x = dpp_add<0x141>(x);  // half-mirror (== xor4 after 4-uniformity)
  x = dpp_add<0x140>(x);  // mirror (== xor8 after 8-uniformity)
  return x;
}

// async global->LDS DMA, 16 B per lane (dest = wave-uniform base + lane*16)
__device__ __forceinline__ void gl2lds16(const float* g, float* l) {
  __builtin_amdgcn_global_load_lds(
      (const __attribute__((address_space(1))) void*)g,
      (__attribute__((address_space(3))) void*)l, 16, 0, 0);
}

// ---------------------------------------------------------------------------
// Kernel 1: h1t[f][tok] = relu(relu(actions@w0 + b0)@w1 + b1)  (TRANSPOSED out)
// ---------------------------------------------------------------------------
__global__ __launch_bounds__(256) void k_mlp01(
    const float* __restrict__ actions, const float* __restrict__ w0,
    const float* __restrict__ b0, const float* __restrict__ w1,
    const float* __restrict__ b1, float* __restrict__ h1t,
    int s_base, int M)
{
  __shared__ float a_t[DA][64];    // [k][tok]   8 KB
  __shared__ float w0_l[DA][DH];   // [k][f]    16 KB
  __shared__ float h0t[DH][64];    // [f][tok]  32 KB
  const int tid = threadIdx.x;
  const int m0 = blockIdx.x * 64;

#pragma unroll
  for (int q = 0; q < 2; ++q) {
    int g = tid + 256 * q;
    int tok = g >> 3, kq = g & 7;
    int tl = m0 + tok;
    int b = tl & 31, s = s_base + (tl >> 5);
    float4 v = *(const float4*)(actions + ((size_t)b * S_ + s) * DA + 4 * kq);
    a_t[4 * kq + 0][tok] = v.x; a_t[4 * kq + 1][tok] = v.y;
    a_t[4 * kq + 2][tok] = v.z; a_t[4 * kq + 3][tok] = v.w;
  }
#pragma unroll
  for (int q = 0; q < 4; ++q) {
    int g = tid + 256 * q;
    ((float4*)&w0_l[0][0])[g] = ((const float4*)w0)[g];
  }
  __syncthreads();

  const int tm = tid & 15;
  const int tn = tid >> 4;

  float acc[4][8];
#pragma unroll
  for (int mi = 0; mi < 4; ++mi)
#pragma unroll
    for (int ni = 0; ni < 8; ++ni) acc[mi][ni] = 0.f;

#pragma unroll 4
  for (int k = 0; k < DA; ++k) {
    float4 a4 = *(const float4*)&a_t[k][4 * tm];
    float4 wa = *(const float4*)&w0_l[k][8 * tn];
    float4 wb = *(const float4*)&w0_l[k][8 * tn + 4];
    float av[4] = {a4.x, a4.y, a4.z, a4.w};
    float wv[8] = {wa.x, wa.y, wa.z, wa.w, wb.x, wb.y, wb.z, wb.w};
#pragma unroll
    for (int mi = 0; mi < 4; ++mi)
#pragma unroll
      for (int ni = 0; ni < 8; ++ni) acc[mi][ni] += av[mi] * wv[ni];
  }
  {
    float4 ba = *(const float4*)(b0 + 8 * tn);
    float4 bb = *(const float4*)(b0 + 8 * tn + 4);
    float bv[8] = {ba.x, ba.y, ba.z, ba.w, bb.x, bb.y, bb.z, bb.w};
#pragma unroll
    for (int mi = 0; mi < 4; ++mi)
#pragma unroll
      for (int ni = 0; ni < 8; ++ni)
        h0t[8 * tn + ni][4 * tm + mi] = fmaxf(acc[mi][ni] + bv[ni], 0.f);
  }
  __syncthreads();

  float acc1[4][8];
#pragma unroll
  for (int mi = 0; mi < 4; ++mi)
#pragma unroll
    for (int ni = 0; ni < 8; ++ni) acc1[mi][ni] = 0.f;

#pragma unroll 4
  for (int k = 0; k < DH; ++k) {
    float4 h4 = *(const float4*)&h0t[k][4 * tm];
    float4 wa = *(const float4*)(w1 + (size_t)k * DH + 8 * tn);
    float4 wb = *(const float4*)(w1 + (size_t)k * DH + 8 * tn + 4);
    float av[4] = {h4.x, h4.y, h4.z, h4.w};
    float wv[8] = {wa.x, wa.y, wa.z, wa.w, wb.x, wb.y, wb.z, wb.w};
#pragma unroll
    for (int mi = 0; mi < 4; ++mi)
#pragma unroll
      for (int ni = 0; ni < 8; ++ni) acc1[mi][ni] += av[mi] * wv[ni];
  }
  {
    float4 ba = *(const float4*)(b1 + 8 * tn);
    float4 bb = *(const float4*)(b1 + 8 * tn + 4);
    float bv[8] = {ba.x, ba.y, ba.z, ba.w, bb.x, bb.y, bb.z, bb.w};
#pragma unroll
    for (int ni = 0; ni < 8; ++ni) {
      float4 o;
      o.x = fmaxf(acc1[0][ni] + bv[ni], 0.f);
      o.y = fmaxf(acc1[1][ni] + bv[ni], 0.f);
      o.z = fmaxf(acc1[2][ni] + bv[ni], 0.f);
      o.w = fmaxf(acc1[3][ni] + bv[ni], 0.f);
      *(float4*)(h1t + (size_t)(8 * tn + ni) * M + m0 + 4 * tm) = o;
    }
  }
}

// ---------------------------------------------------------------------------
// Kernel 2: trans = h1t^T @ w2 + b2.  fp32, 256 threads, tile 128x128,
// microtile 8m x 8n, acc=64 regs.  Staging via global_load_lds (no VGPR
// round-trip, no staging registers -> fits 128-VGPR cap, 4 waves/SIMD).
// TKK=16 double-buffered (32 KB).  m97 order: sync; async-load t+1; compute t.
// Thread map: mg=tid>>4 (m=8mg, A broadcast), ng=tid&15 (n=64q+4ng+r) ->
// B-reads 2-way-free, stores 256 B contiguous per 16-lane group.
// ---------------------------------------------------------------------------
#define TKK 16
__global__ __launch_bounds__(256, 2) void k_trans(
    const float* __restrict__ h1t, const float* __restrict__ w2,
    const float* __restrict__ b2, float* __restrict__ trans, int M)
{
  __shared__ float As[2][TKK][128];  // 8 KB x2
  __shared__ float Bs[2][TKK][128];  // 8 KB x2
  const int tid = threadIdx.x;
  const int n0 = blockIdx.x * 128;
  const int m0 = blockIdx.y * 128;
  const int w  = tid >> 6;     // wave id 0..3
  const int lw = tid & 63;     // lane

  // async stage of K-tile t into buffer buf: 8 A-instrs + 8 B-instrs,
  // instr i covers rows 2i,2i+1 (1024 B); wave w issues i = 2w, 2w+1.
  auto aload = [&](int t, int buf) {
#pragma unroll
    for (int ii = 0; ii < 2; ++ii) {
      const int i = 2 * w + ii;
      const int kr = 2 * i + (lw >> 5);        // k-row this lane feeds
      const int c4 = 4 * (lw & 31);            // col offset (16 B granule)
      gl2lds16(h1t + (size_t)(t * TKK + kr) * M + m0 + c4, &As[buf][2 * i][0]);
      gl2lds16(w2 + (size_t)(t * TKK + kr) * DS2 + n0 + c4, &Bs[buf][2 * i][0]);
    }
  };

  aload(0, 0);

  const int mg = tid >> 4;   // 0..15, m = 8*mg+mi
  const int ng = tid & 15;   // n = 64*q + 4*ng + r, q = 0..1
  float acc[8][8];
#pragma unroll
  for (int mi = 0; mi < 8; ++mi)
#pragma unroll
    for (int ni = 0; ni < 8; ++ni) acc[mi][ni] = 0.f;

  int buf = 0;
  for (int t = 0; t < DH / TKK; ++t) {
    __syncthreads();                      // drains vmcnt: buf's tile visible
    if (t < DH / TKK - 1) aload(t + 1, buf ^ 1);  // lands during compute
#pragma unroll
    for (int k = 0; k < TKK; ++k) {
      float4 a0 = *(const float4*)&As[buf][k][8 * mg];
      float4 a1 = *(const float4*)&As[buf][k][8 * mg + 4];
      float av[8] = {a0.x, a0.y, a0.z, a0.w, a1.x, a1.y, a1.z, a1.w};
      float4 b0v = *(const float4*)&Bs[buf][k][4 * ng];
      float4 b1v = *(const float4*)&Bs[buf][k][64 + 4 * ng];
      float bv[8] = {b0v.x, b0v.y, b0v.z, b0v.w, b1v.x, b1v.y, b1v.z, b1v.w};
#pragma unroll
      for (int mi = 0; mi < 8; ++mi)
#pragma unroll
        for (int ni = 0; ni < 8; ++ni) acc[mi][ni] += av[mi] * bv[ni];
    }
    buf ^= 1;
  }

  float4 bb0 = *(const float4*)(b2 + n0 + 4 * ng);
  float4 bb1 = *(const float4*)(b2 + n0 + 64 + 4 * ng);
  float bv[8] = {bb0.x, bb0.y, bb0.z, bb0.w, bb1.x, bb1.y, bb1.z, bb1.w};
#pragma unroll
  for (int mi = 0; mi < 8; ++mi) {
    float* dst = trans + (size_t)(m0 + 8 * mg + mi) * DS2 + n0;
#pragma unroll
    for (int q = 0; q < 2; ++q) {
      float4 o;
      o.x = acc[mi][4 * q + 0] + bv[4 * q + 0];
      o.y = acc[mi][4 * q + 1] + bv[4 * q + 1];
      o.z = acc[mi][4 * q + 2] + bv[4 * q + 2];
      o.w = acc[mi][4 * q + 3] + bv[4 * q + 3];
      *(float4*)(dst + 64 * q + 4 * ng) = o;  // 256 B contig / 16-lane group
    }
  }
}

// ---------------------------------------------------------------------------
// Kernel 3: sequential RNN.  One wave per batch element.
// float4 T layout: lane l holds T[i=4q+(l>>4)][j=4(l&15)..+3], q=0..15
// (16 dwordx4 coalesced loads/step).  Ring of 3 slots (192 VGPR, under the
// 256 arch cap).  h broadcast: per-lane-indexed __shfl (ds_bpermute) with
// src=(lane&48)+q — lane 16d+q's hsel (own component d) == h_{4q+d}.
// Cross-d reduce: shfl_xor 16/32.  Norm: 4 DPP row-adds.
// ---------------------------------------------------------------------------
__global__ __launch_bounds__(64, 1) void k_rnn(
    const float* __restrict__ trans, const float* __restrict__ init_hidden,
    float* __restrict__ hstate, float* __restrict__ out,
    int s_base, int SC, int chunk)
{
  const int lane = threadIdx.x;
  const int b = blockIdx.x;
  const int d = lane >> 4;          // 0..3 (replica group / i mod 4)
  const int c = lane & 15;          // j-quad index
  const bool d1 = (d & 1), d2 = (d & 2);
  const int pb = lane & 48;         // bpermute base (16*d)

  float4 hq;                        // h[4c..4c+3], replicated across d
  if (chunk == 0) {
    hq = *(const float4*)(init_hidden + 4 * c);
    float ss = row_sum16(hq.x * hq.x + hq.y * hq.y + hq.z * hq.z + hq.w * hq.w);
    float inv = 1.0f / fmaxf(sqrtf(ss), 1e-12f);
    hq.x *= inv; hq.y *= inv; hq.z *= inv; hq.w *= inv;
  } else {
    hq = *(const float4*)(hstate + b * DS + 4 * c);
  }

  // per-step block base (floats): (s*32+b)*4096 ; lane term 4*lane
  const float* tb = trans + (size_t)b * DS2 + 4 * lane;
  float4 sl0[16], sl1[16], sl2[16];

#define PRELOAD(SLOT, sidx)                                                   \
  {                                                                           \
    const float* _p = tb + (size_t)(sidx) * (32 * DS2);                       \
    _Pragma("unroll")                                                         \
    for (int q = 0; q < 16; ++q) SLOT[q] = *(const float4*)(_p + q * 256);    \
  }

  PRELOAD(sl0, 0)
  PRELOAD(sl1, 1)
  PRELOAD(sl2, 2)

  float* outp = out + ((size_t)b * S_ + s_base) * DS + 4 * c;

#define RSTEP(SLOT, scur)                                                     \
  {                                                                           \
    float hsel = d2 ? (d1 ? hq.w : hq.z) : (d1 ? hq.y : hq.x);                \
    float ax = 0.f, ay = 0.f, az = 0.f, aw = 0.f;                             \
    _Pragma("unroll")                                                         \
    for (int q = 0; q < 16; ++q) {                                            \
      float hb = __shfl(hsel, pb + q, 64);                                    \
      ax += hb * SLOT[q].x; ay += hb * SLOT[q].y;                             \
      az += hb * SLOT[q].z; aw += hb * SLOT[q].w;                             \
    }                                                                         \
    int sp = (scur) + 3; if (sp > SC - 1) sp = SC - 1;                        \
    PRELOAD(SLOT, sp)                                                         \
    ax += __shfl_xor(ax, 16, 64); ax += __shfl_xor(ax, 32, 64);               \
    ay += __shfl_xor(ay, 16, 64); ay += __shfl_xor(ay, 32, 64);               \
    az += __shfl_xor(az, 16, 64); az += __shfl_xor(az, 32, 64);               \
    aw += __shfl_xor(aw, 16, 64); aw += __shfl_xor(aw, 32, 64);               \
    ax = fmaxf(ax, 0.f); ay = fmaxf(ay, 0.f);                                 \
    az = fmaxf(az, 0.f); aw = fmaxf(aw, 0.f);                                 \
    float ss = row_sum16(ax * ax + ay * ay + az * az + aw * aw);              \
    float inv = 1.0f / fmaxf(sqrtf(ss), 1e-12f);                              \
    hq.x = ax * inv; hq.y = ay * inv; hq.z = az * inv; hq.w = aw * inv;       \
    if (d == 0) *(float4*)(outp + (size_t)(scur) * DS) = hq;                  \
  }

  int s0 = 0;
  for (; s0 + 3 <= SC; s0 += 3) {
    RSTEP(sl0, s0)
    RSTEP(sl1, s0 + 1)
    RSTEP(sl2, s0 + 2)
  }
  if (SC - s0 >= 1) RSTEP(sl0, s0)
  if (SC - s0 >= 2) RSTEP(sl1, s0 + 1)

  if (d == 0) *(float4*)(hstate + b * DS + 4 * c) = hq;
#undef PRELOAD
#undef RSTEP
}

// ---------------------------------------------------------------------------
extern "C" void kernel_launch(void* const* d_in, const int* in_sizes, int n_in,
                              void* d_out, int out_size, void* d_ws, size_t ws_size,
                              hipStream_t stream) {
  const float* actions     = (const float*)d_in[0];
  const float* w0          = (const float*)d_in[1];
  const float* b0          = (const float*)d_in[2];
  const float* w1          = (const float*)d_in[3];
  const float* b1          = (const float*)d_in[4];
  const float* w2          = (const float*)d_in[5];
  const float* b2          = (const float*)d_in[6];
  const float* init_hidden = (const float*)d_in[7];
  float* out = (float*)d_out;

  // pick the largest sequence chunk whose transitions fit in ws
  int SC = 2048;
  while (SC > 4) {
    size_t need = (size_t)SC * 32 * DS2 * 4   // transitions chunk
                + (size_t)SC * 32 * DH * 4    // h1t chunk
                + 64 * 4;                     // hidden-state carry
    if (need <= ws_size) break;
    SC >>= 1;
  }
  float* trans  = (float*)d_ws;
  float* h1t    = trans + (size_t)SC * 32 * DS2;
  float* hstate = h1t + (size_t)SC * 32 * DH;

  const int M = SC * 32;
  const int nch = S_ / SC;
  for (int c = 0; c < nch; ++c) {
    int s_base = c * SC;
    hipLaunchKernelGGL(k_mlp01, dim3(M / 64), dim3(256), 0, stream,
                       actions, w0, b0, w1, b1, h1t, s_base, M);
    hipLaunchKernelGGL(k_trans, dim3(DS2 / 128, M / 128), dim3(256), 0, stream,
                       h1t, w2, b2, trans, M);
    hipLaunchKernelGGL(k_rnn, dim3(32), dim3(64), 0, stream,
                       trans, init_hidden, hstate, out, s_base, SC, c);
  }
}